// Round 6
// baseline (217.919 us; speedup 1.0000x reference)
//
#include <hip/hip_runtime.h>
#include <cstdint>
#include <cstddef>

// Problem dims (fixed by the reference setup_inputs):
#define B_DIM   8192
#define IN_DIM  1024
#define OUT_DIM 4096
#define KT2     (IN_DIM / 64)    // 16 panels (of K=64) per 32-row tile

typedef __attribute__((ext_vector_type(8)))  int   i32x8;   // fp8 MFMA A/B frag (32 B)
typedef __attribute__((ext_vector_type(4)))  int   i32x4;
typedef __attribute__((ext_vector_type(16))) float f32x16;  // 32x32 MFMA accumulator

// async global->LDS DMA, 16B per lane. LDS dest is wave-uniform base + lane*16.
__device__ __forceinline__ void async_copy16(const void* gptr, void* ldsptr) {
    __builtin_amdgcn_global_load_lds(
        (__attribute__((address_space(1))) void*)gptr,
        (__attribute__((address_space(3))) void*)ldsptr,
        16, 0, 0);
}

// pack 4 fp32 -> 4 OCP e4m3 bytes (little-endian k order)
__device__ __forceinline__ int pack4_fp8(float a, float b, float c, float d) {
    int pk = __builtin_amdgcn_cvt_pk_fp8_f32(a, b, 0, false);   // bytes 0-1
    pk = __builtin_amdgcn_cvt_pk_fp8_f32(c, d, pk, true);       // bytes 2-3
    return pk;
}

// fp8 panel: 32 rows x 64 k = 2048 B. Lane l owns row m=l&31, k=(l>>5)*32+[0,32).
// Half h (k-bytes [h*16,h*16+16)) lives at panel + h*1024 + l*16: staging is two
// fully-linear global_load_lds, frag reads two ds_read_b128 (conflict-free).

// ---------------------------------------------------------------------------
// Kernel 1 (merged quantizer): 1024 blocks x 256 threads (~4 blocks/CU).
//  b < 512 : X-quant. mt = b>>1 (32 rows), kh = b&1 (k-half). Wave w emits
//            panels kt2 = kh*8 + w*2 + {0,1}; xsq partial -> xsq2[kh][m].
//  b >= 512: W-quant. nt = (b-512)&127, q = (b-512)>>7 (k-quarter). LDS
//            transpose, wave w emits panel kt2 = q*4+w; partial -> wsq2[q][n].
// All norm outputs are PURE STORES (no atomics, no zero-fill, no cross-block
// ordering) — partials are summed in the GEMM epilogue.
// ---------------------------------------------------------------------------
__global__ __launch_bounds__(256) void quant_kernel(
    const float* __restrict__ x, const float* __restrict__ wgt,
    unsigned char* __restrict__ At, unsigned char* __restrict__ Bt,
    float* __restrict__ xsq2,     // [2][B_DIM]
    float* __restrict__ wsq2)     // [4][OUT_DIM]
{
    __shared__ float tile[256 * 33];      // W-path transpose tile ([k][n], pad 33)
    __shared__ float red[4][32];

    const int t = threadIdx.x;
    const int w = t >> 6;                 // 0..3
    const int l = t & 63;
    const int b = blockIdx.x;

    if (b < 512) {
        // ---- X-quant ----
        const int mt = b >> 1, kh = b & 1;
        const int m  = mt * 32 + (l & 31);
        float s = 0.0f;
        #pragma unroll
        for (int p = 0; p < 2; ++p) {
            const int kt2 = kh * 8 + w * 2 + p;
            const float* src = x + (size_t)m * IN_DIM + kt2 * 64 + (l >> 5) * 32;
            i32x4 lo, hi;
            #pragma unroll
            for (int j = 0; j < 4; ++j) {
                float4 v = ((const float4*)src)[j];
                s += v.x*v.x + v.y*v.y + v.z*v.z + v.w*v.w;
                lo[j] = pack4_fp8(v.x, v.y, v.z, v.w);
            }
            #pragma unroll
            for (int j = 0; j < 4; ++j) {
                float4 v = ((const float4*)src)[4 + j];
                s += v.x*v.x + v.y*v.y + v.z*v.z + v.w*v.w;
                hi[j] = pack4_fp8(v.x, v.y, v.z, v.w);
            }
            unsigned char* pan = At + ((size_t)mt * KT2 + kt2) * 2048;
            *(i32x4*)(pan + l * 16)        = lo;
            *(i32x4*)(pan + 1024 + l * 16) = hi;
        }
        s += __shfl_down(s, 32, 64);      // lanes l, l+32 = same row's k-slices
        if (l < 32) red[w][l] = s;
        __syncthreads();
        if (t < 32)
            xsq2[kh * B_DIM + mt * 32 + t] =
                red[0][t] + red[1][t] + red[2][t] + red[3][t];
    } else {
        // ---- W-quant ----
        const int idx = b - 512;
        const int nt = idx & 127, q = idx >> 7, n0 = nt * 32;

        const int rbase = t >> 2, cg = (t & 3) * 8;
        #pragma unroll
        for (int rep = 0; rep < 4; ++rep) {
            const int r = rbase + rep * 64;
            const float* src = wgt + (size_t)(q * 256 + r) * OUT_DIM + n0 + cg;
            float4 v0 = ((const float4*)src)[0];
            float4 v1 = ((const float4*)src)[1];
            float* d = &tile[r * 33 + cg];
            d[0] = v0.x; d[1] = v0.y; d[2] = v0.z; d[3] = v0.w;
            d[4] = v1.x; d[5] = v1.y; d[6] = v1.z; d[7] = v1.w;
        }
        __syncthreads();

        const int kt2 = q * 4 + w;
        const int n   = l & 31;
        const int kb  = w * 64 + (l >> 5) * 32;
        float s = 0.0f;
        i32x4 lo, hi;
        #pragma unroll
        for (int j4 = 0; j4 < 4; ++j4) {
            float f0 = tile[(kb + j4 * 4 + 0) * 33 + n];
            float f1 = tile[(kb + j4 * 4 + 1) * 33 + n];
            float f2 = tile[(kb + j4 * 4 + 2) * 33 + n];
            float f3 = tile[(kb + j4 * 4 + 3) * 33 + n];
            s += f0*f0 + f1*f1 + f2*f2 + f3*f3;
            lo[j4] = pack4_fp8(f0, f1, f2, f3);
        }
        #pragma unroll
        for (int j4 = 0; j4 < 4; ++j4) {
            float f0 = tile[(kb + 16 + j4 * 4 + 0) * 33 + n];
            float f1 = tile[(kb + 16 + j4 * 4 + 1) * 33 + n];
            float f2 = tile[(kb + 16 + j4 * 4 + 2) * 33 + n];
            float f3 = tile[(kb + 16 + j4 * 4 + 3) * 33 + n];
            s += f0*f0 + f1*f1 + f2*f2 + f3*f3;
            hi[j4] = pack4_fp8(f0, f1, f2, f3);
        }
        unsigned char* pan = Bt + ((size_t)nt * KT2 + kt2) * 2048;
        *(i32x4*)(pan + l * 16)        = lo;
        *(i32x4*)(pan + 1024 + l * 16) = hi;

        s += __shfl_down(s, 32, 64);      // combine k-halves of same n
        if (l < 32) red[w][l] = s;
        __syncthreads();
        if (t < 32)
            wsq2[q * OUT_DIM + n0 + t] =
                red[0][t] + red[1][t] + red[2][t] + red[3][t];
    }
}

// ---------------------------------------------------------------------------
// Kernel 2: MX-fp8 GEMM, PERSISTENT 2-TILE blocks. Grid 512 x 256 thr, 72 KB
// LDS -> 2 blocks/CU, exactly ONE residency round. Each block: two 128x256
// tiles (same bm, bn = 2*bnp+tt). At the tile boundary, tile-1's k0/k1 stages
// are issued BEFORE tile-0's epilogue store burst, so the 67 MB of tile-0
// writes drain UNDER tile-1's K-loop MFMAs (in-order vmcnt retirement makes
// iters 0-1 of tile 1 need no wait at all: the epilogue's xs/wsq data-waits
// already retired L0/L1, and the iter barrier is the cross-wave certification).
// K-loop: 3-buf, counted vmcnt(6) (T3/T4), setprio (T5), XCD swizzle (T1).
// ---------------------------------------------------------------------------
__global__ __launch_bounds__(256, 2) void rbf_gemm_kernel(
    const unsigned char* __restrict__ At,   // [256*KT2][2048]
    const unsigned char* __restrict__ Bt,   // [128*KT2][2048]
    const float* __restrict__ xsq2,         // [2][B_DIM]
    const float* __restrict__ wsq2,         // [4][OUT_DIM]
    float* __restrict__ out)
{
    __shared__ __align__(16) unsigned char sm[73728];   // 3 x (4 A + 8 B panels)

    const int t    = threadIdx.x;
    const int w    = t >> 6;              // 0..3 (waveCol)
    const int l    = t & 63;
    const int l32  = l & 31;
    const int half = l >> 5;

    // XCD-bijective swizzle: 512 wgs, 512 % 8 == 0. XCD x gets bm in
    // [x*8, x*8+8), all bnp (A slice 1 MB + B 4 MB ~ L2-resident per XCD).
    const int wg  = blockIdx.x;           // 0..511
    const int swz = (wg & 7) * 64 + (wg >> 3);
    const int bm  = swz >> 3;             // 0..63
    const int bnp = swz & 7;              // 0..7 -> tiles bn = 2*bnp+{0,1}

    // wave w stages A panel w and B panels 2w, 2w+1: 6 linear DMAs per K-step.
    const unsigned char* gaBase = At + (size_t)(bm * 4 + w) * (KT2 * 2048);

    auto ldfrag = [&](const unsigned char* base, int p) -> i32x8 {
        i32x4 lo = *(const i32x4*)(base + p * 2048 + l * 16);
        i32x4 hi = *(const i32x4*)(base + p * 2048 + 1024 + l * 16);
        i32x8 r;
        r[0] = lo[0]; r[1] = lo[1]; r[2] = lo[2]; r[3] = lo[3];
        r[4] = hi[0]; r[5] = hi[1]; r[6] = hi[2]; r[7] = hi[3];
        return r;
    };

    #pragma unroll
    for (int tt = 0; tt < 2; ++tt) {
        const int bn = bnp * 2 + tt;      // 0..15
        const unsigned char* gbBase0 = Bt + (size_t)(bn * 8 + w * 2) * (KT2 * 2048);
        const unsigned char* gbBase1 = gbBase0 + (size_t)(KT2 * 2048);

        auto stage = [&](int buf, int k) {
            unsigned char* As = sm + buf * 24576;
            unsigned char* Bs = As + 8192;
            const unsigned char* ga  = gaBase  + k * 2048;
            const unsigned char* gb0 = gbBase0 + k * 2048;
            const unsigned char* gb1 = gbBase1 + k * 2048;
            #pragma unroll
            for (int h = 0; h < 2; ++h) {
                async_copy16(ga  + h * 1024 + l * 16, As + w * 2048 + h * 1024);
                async_copy16(gb0 + h * 1024 + l * 16, Bs + (w * 2 + 0) * 2048 + h * 1024);
                async_copy16(gb1 + h * 1024 + l * 16, Bs + (w * 2 + 1) * 2048 + h * 1024);
            }
        };

        f32x16 acc[4][2];
        #pragma unroll
        for (int mi = 0; mi < 4; ++mi)
            #pragma unroll
            for (int ni = 0; ni < 2; ++ni)
                #pragma unroll
                for (int r = 0; r < 16; ++r)
                    acc[mi][ni][r] = 0.0f;

        if (tt == 0) {                    // tile-1's k0/k1 staged at the boundary
            stage(0, 0);                  // 6 DMAs
            stage(1, 1);                  // 6 DMAs (12 in flight)
        }

        int cb = 0, sb = 2;               // compute buf = k%3, stage buf = (k+2)%3
        for (int k = 0; k < 16; ++k) {
            if (tt == 1 && k < 2) {
                // no vmcnt needed: L0/L1 were issued before tile-0's epilogue,
                // whose data-waits retired them (in-order); barrier certifies
                // cross-wave. Residual epilogue stores stay in flight.
            } else if (k < 15) {
                // own stage(k) retired: outstanding = stage(k)+stage(k+1)=12 -> 6.
                asm volatile("s_waitcnt vmcnt(6)" ::: "memory");
            } else {
                asm volatile("s_waitcnt vmcnt(0)" ::: "memory");
            }
            __builtin_amdgcn_s_barrier();              // all waves' stage(k) landed
            __builtin_amdgcn_sched_barrier(0);         // no ds_read hoists above

            // WAR-safe: buf (k+2)%3 last read at iter k-1; barrier orders it.
            if (k <= 13) stage(sb, k + 2);

            const unsigned char* As = sm + cb * 24576;
            const unsigned char* Bs = As + 8192;
            i32x8 bf0 = ldfrag(Bs, w * 2 + 0);
            i32x8 bf1 = ldfrag(Bs, w * 2 + 1);
            i32x8 af[4];
            #pragma unroll
            for (int mi = 0; mi < 4; ++mi)
                af[mi] = ldfrag(As, mi);

            __builtin_amdgcn_s_setprio(1);
            #pragma unroll
            for (int mi = 0; mi < 4; ++mi) {
                acc[mi][0] = __builtin_amdgcn_mfma_scale_f32_32x32x64_f8f6f4(
                    af[mi], bf0, acc[mi][0],
                    0, 0,                 // cbsz=fp8(e4m3), blgp=fp8(e4m3)
                    0, 0x7F7F7F7F,        // A scales = 1.0 (E8M0 127)
                    0, 0x7F7F7F7F);       // B scales = 1.0
                acc[mi][1] = __builtin_amdgcn_mfma_scale_f32_32x32x64_f8f6f4(
                    af[mi], bf1, acc[mi][1],
                    0, 0, 0, 0x7F7F7F7F, 0, 0x7F7F7F7F);
            }
            __builtin_amdgcn_s_setprio(0);

            cb = (cb == 2) ? 0 : cb + 1;
            sb = (sb == 2) ? 0 : sb + 1;
        }

        if (tt == 0) {
            // every wave's iter-15 ds_reads completed (lgkm waits before MFMA),
            // so after this barrier restaging buf0/buf1 cannot race any reader.
            __builtin_amdgcn_s_barrier();
            // Issue tile-1's k0/k1 NOW (12 loads), BEFORE the store burst:
            const unsigned char* nb0 = Bt + (size_t)((bnp * 2 + 1) * 8 + w * 2) * (KT2 * 2048);
            const unsigned char* nb1 = nb0 + (size_t)(KT2 * 2048);
            #pragma unroll
            for (int k = 0; k < 2; ++k) {
                unsigned char* As = sm + k * 24576;
                unsigned char* Bs = As + 8192;
                #pragma unroll
                for (int h = 0; h < 2; ++h) {
                    async_copy16(gaBase + k * 2048 + h * 1024 + l * 16, As + w * 2048 + h * 1024);
                    async_copy16(nb0    + k * 2048 + h * 1024 + l * 16, Bs + (w * 2 + 0) * 2048 + h * 1024);
                    async_copy16(nb1    + k * 2048 + h * 1024 + l * 16, Bs + (w * 2 + 1) * 2048 + h * 1024);
                }
            }
        }

        // Epilogue tile tt. 32x32 C/D layout: col(n)=lane&31,
        // row(m)=(r&3)+8*(r>>2)+4*(l>>5). For tt==0 these stores drain under
        // tile-1's K-loop.
        const int ncol = bn * 256 + w * 64 + l32;
        const float wsn0 = wsq2[ncol]      + wsq2[OUT_DIM + ncol]
                         + wsq2[2 * OUT_DIM + ncol]      + wsq2[3 * OUT_DIM + ncol];
        const float wsn1 = wsq2[ncol + 32] + wsq2[OUT_DIM + ncol + 32]
                         + wsq2[2 * OUT_DIM + ncol + 32] + wsq2[3 * OUT_DIM + ncol + 32];
        #pragma unroll
        for (int mi = 0; mi < 4; ++mi) {
            const int mbase = bm * 128 + mi * 32 + 4 * half;
            #pragma unroll
            for (int r2 = 0; r2 < 4; ++r2) {
                #pragma unroll
                for (int r1 = 0; r1 < 4; ++r1) {
                    const int m  = mbase + r1 + 8 * r2;
                    const float xs = xsq2[m] + xsq2[B_DIM + m];
                    float* orow = out + (size_t)m * OUT_DIM + ncol;
                    orow[0]  = xs + wsn0 - 2.0f * acc[mi][0][r2 * 4 + r1];
                    orow[32] = xs + wsn1 - 2.0f * acc[mi][1][r2 * 4 + r1];
                }
            }
        }
    }
}

// ---------------------------------------------------------------------------
extern "C" void kernel_launch(void* const* d_in, const int* in_sizes, int n_in,
                              void* d_out, int out_size, void* d_ws, size_t ws_size,
                              hipStream_t stream)
{
    const float* x   = (const float*)d_in[0];   // (8192, 1024) fp32
    const float* wgt = (const float*)d_in[1];   // (1024, 4096) fp32
    float* out = (float*)d_out;                 // (8192, 4096) fp32
    char*  ws  = (char*)d_ws;

    // workspace: At (8 MB) | Bt (4 MB) | xsq2 (64 KB) | wsq2 (64 KB)
    unsigned char* At = (unsigned char*)ws;
    unsigned char* Bt = (unsigned char*)(ws + (size_t)B_DIM * IN_DIM);
    float* xsq2 = (float*)(ws + (size_t)B_DIM * IN_DIM + (size_t)OUT_DIM * IN_DIM);
    float* wsq2 = xsq2 + 2 * B_DIM;

    quant_kernel<<<1024, 256, 0, stream>>>(x, wgt, At, Bt, xsq2, wsq2);
    rbf_gemm_kernel<<<512, 256, 0, stream>>>(At, Bt, xsq2, wsq2, out);
}

// Round 7
// 192.352 us; speedup vs baseline: 1.1329x; 1.1329x over previous
//
#include <hip/hip_runtime.h>
#include <cstdint>
#include <cstddef>

// Problem dims (fixed by the reference setup_inputs):
#define B_DIM   8192
#define IN_DIM  1024
#define OUT_DIM 4096
#define KT2     (IN_DIM / 64)    // 16 panels (of K=64) per 32-row tile

typedef __attribute__((ext_vector_type(8)))  int   i32x8;   // fp8 MFMA A/B frag (32 B)
typedef __attribute__((ext_vector_type(4)))  int   i32x4;
typedef __attribute__((ext_vector_type(16))) float f32x16;  // 32x32 MFMA accumulator

// async global->LDS DMA, 16B per lane. LDS dest is wave-uniform base + lane*16.
__device__ __forceinline__ void async_copy16(const void* gptr, void* ldsptr) {
    __builtin_amdgcn_global_load_lds(
        (__attribute__((address_space(1))) void*)gptr,
        (__attribute__((address_space(3))) void*)ldsptr,
        16, 0, 0);
}

// pack 4 fp32 -> 4 OCP e4m3 bytes (little-endian k order)
__device__ __forceinline__ int pack4_fp8(float a, float b, float c, float d) {
    int pk = __builtin_amdgcn_cvt_pk_fp8_f32(a, b, 0, false);   // bytes 0-1
    pk = __builtin_amdgcn_cvt_pk_fp8_f32(c, d, pk, true);       // bytes 2-3
    return pk;
}

// fp8 panel: 32 rows x 64 k = 2048 B. Lane l owns row m=l&31, k=(l>>5)*32+[0,32).
// Half h (k-bytes [h*16,h*16+16)) lives at panel + h*1024 + l*16: staging is two
// fully-linear global_load_lds, frag reads two ds_read_b128 (conflict-free).

// ---------------------------------------------------------------------------
// Kernel 1 (merged quantizer): 1024 blocks x 256 threads (~4 blocks/CU).
//  b < 512 : X-quant. mt = b>>1 (32 rows), kh = b&1 (k-half). Wave w emits
//            panels kt2 = kh*8 + w*2 + {0,1}; xsq partial -> xsq2[kh][m].
//  b >= 512: W-quant. nt = (b-512)&127, q = (b-512)>>7 (k-quarter). LDS
//            transpose, wave w emits panel kt2 = q*4+w; partial -> wsq2[q][n].
// All norm outputs are PURE STORES (no atomics, no zero-fill, no cross-block
// ordering) — partials are summed in the GEMM epilogue.
// ---------------------------------------------------------------------------
__global__ __launch_bounds__(256) void quant_kernel(
    const float* __restrict__ x, const float* __restrict__ wgt,
    unsigned char* __restrict__ At, unsigned char* __restrict__ Bt,
    float* __restrict__ xsq2,     // [2][B_DIM]
    float* __restrict__ wsq2)     // [4][OUT_DIM]
{
    __shared__ float tile[256 * 33];      // W-path transpose tile ([k][n], pad 33)
    __shared__ float red[4][32];

    const int t = threadIdx.x;
    const int w = t >> 6;                 // 0..3
    const int l = t & 63;
    const int b = blockIdx.x;

    if (b < 512) {
        // ---- X-quant ----
        const int mt = b >> 1, kh = b & 1;
        const int m  = mt * 32 + (l & 31);
        float s = 0.0f;
        #pragma unroll
        for (int p = 0; p < 2; ++p) {
            const int kt2 = kh * 8 + w * 2 + p;
            const float* src = x + (size_t)m * IN_DIM + kt2 * 64 + (l >> 5) * 32;
            i32x4 lo, hi;
            #pragma unroll
            for (int j = 0; j < 4; ++j) {
                float4 v = ((const float4*)src)[j];
                s += v.x*v.x + v.y*v.y + v.z*v.z + v.w*v.w;
                lo[j] = pack4_fp8(v.x, v.y, v.z, v.w);
            }
            #pragma unroll
            for (int j = 0; j < 4; ++j) {
                float4 v = ((const float4*)src)[4 + j];
                s += v.x*v.x + v.y*v.y + v.z*v.z + v.w*v.w;
                hi[j] = pack4_fp8(v.x, v.y, v.z, v.w);
            }
            unsigned char* pan = At + ((size_t)mt * KT2 + kt2) * 2048;
            *(i32x4*)(pan + l * 16)        = lo;
            *(i32x4*)(pan + 1024 + l * 16) = hi;
        }
        s += __shfl_down(s, 32, 64);      // lanes l, l+32 = same row's k-slices
        if (l < 32) red[w][l] = s;
        __syncthreads();
        if (t < 32)
            xsq2[kh * B_DIM + mt * 32 + t] =
                red[0][t] + red[1][t] + red[2][t] + red[3][t];
    } else {
        // ---- W-quant ----
        const int idx = b - 512;
        const int nt = idx & 127, q = idx >> 7, n0 = nt * 32;

        const int rbase = t >> 2, cg = (t & 3) * 8;
        #pragma unroll
        for (int rep = 0; rep < 4; ++rep) {
            const int r = rbase + rep * 64;
            const float* src = wgt + (size_t)(q * 256 + r) * OUT_DIM + n0 + cg;
            float4 v0 = ((const float4*)src)[0];
            float4 v1 = ((const float4*)src)[1];
            float* d = &tile[r * 33 + cg];
            d[0] = v0.x; d[1] = v0.y; d[2] = v0.z; d[3] = v0.w;
            d[4] = v1.x; d[5] = v1.y; d[6] = v1.z; d[7] = v1.w;
        }
        __syncthreads();

        const int kt2 = q * 4 + w;
        const int n   = l & 31;
        const int kb  = w * 64 + (l >> 5) * 32;
        float s = 0.0f;
        i32x4 lo, hi;
        #pragma unroll
        for (int j4 = 0; j4 < 4; ++j4) {
            float f0 = tile[(kb + j4 * 4 + 0) * 33 + n];
            float f1 = tile[(kb + j4 * 4 + 1) * 33 + n];
            float f2 = tile[(kb + j4 * 4 + 2) * 33 + n];
            float f3 = tile[(kb + j4 * 4 + 3) * 33 + n];
            s += f0*f0 + f1*f1 + f2*f2 + f3*f3;
            lo[j4] = pack4_fp8(f0, f1, f2, f3);
        }
        #pragma unroll
        for (int j4 = 0; j4 < 4; ++j4) {
            float f0 = tile[(kb + 16 + j4 * 4 + 0) * 33 + n];
            float f1 = tile[(kb + 16 + j4 * 4 + 1) * 33 + n];
            float f2 = tile[(kb + 16 + j4 * 4 + 2) * 33 + n];
            float f3 = tile[(kb + 16 + j4 * 4 + 3) * 33 + n];
            s += f0*f0 + f1*f1 + f2*f2 + f3*f3;
            hi[j4] = pack4_fp8(f0, f1, f2, f3);
        }
        unsigned char* pan = Bt + ((size_t)nt * KT2 + kt2) * 2048;
        *(i32x4*)(pan + l * 16)        = lo;
        *(i32x4*)(pan + 1024 + l * 16) = hi;

        s += __shfl_down(s, 32, 64);      // combine k-halves of same n
        if (l < 32) red[w][l] = s;
        __syncthreads();
        if (t < 32)
            wsq2[q * OUT_DIM + n0 + t] =
                red[0][t] + red[1][t] + red[2][t] + red[3][t];
    }
}

// ---------------------------------------------------------------------------
// Kernel 2: MX-fp8 GEMM (r5 schedule, L2-blocked swizzle). 128x256 tile,
// 4 waves, each wave 128x64 = 4x2 frags of mfma_scale_f32_32x32x64.
// 72 KB LDS (3-buf) -> 2 blocks/CU. Counted s_waitcnt vmcnt(6) + raw
// s_barrier (T3/T4), setprio (T5). Epilogue fuses xsq + wsq - 2*cross.
// ---------------------------------------------------------------------------
__global__ __launch_bounds__(256, 2) void rbf_gemm_kernel(
    const unsigned char* __restrict__ At,   // [256*KT2][2048]
    const unsigned char* __restrict__ Bt,   // [128*KT2][2048]
    const float* __restrict__ xsq2,         // [2][B_DIM]
    const float* __restrict__ wsq2,         // [4][OUT_DIM]
    float* __restrict__ out)
{
    __shared__ __align__(16) unsigned char sm[73728];   // 3 x (4 A + 8 B panels)

    const int t    = threadIdx.x;
    const int w    = t >> 6;              // 0..3 (waveCol)
    const int l    = t & 63;
    const int l32  = l & 31;
    const int half = l >> 5;

    // L2-blocked XCD swizzle (bijective, 1024 % 8 == 0). XCD x owns
    // bm in [x*8, x*8+8) (A slice 1 MB, L2-resident, reused 16x) and
    // iterates bn in GROUPS of 4 (outer bng): live B slice = 1 MB, fetched
    // once per group -> B HBM ~4 MB/XCD, instead of r5's all-16-bn sweep
    // whose 4 MB B working set (= full XCD L2) could thrash vs A + stores.
    // Order per XCD: bng (outer) -> bmi (middle) -> bn-in-group (inner).
    const int wg  = blockIdx.y * 64 + blockIdx.x;   // 0..1023
    const int x8  = wg & 7;               // XCD (dispatch round-robin heuristic)
    const int i   = wg >> 3;              // 0..127 per-XCD sequence
    const int bng = i >> 5;               // 0..3   bn-group of 4
    const int bmi = (i >> 2) & 7;         // 0..7   bm within XCD
    const int bm  = x8 * 8 + bmi;         // 0..63
    const int bn  = bng * 4 + (i & 3);    // 0..15

    f32x16 acc[4][2];
    #pragma unroll
    for (int mi = 0; mi < 4; ++mi)
        #pragma unroll
        for (int ni = 0; ni < 2; ++ni)
            #pragma unroll
            for (int r = 0; r < 16; ++r)
                acc[mi][ni][r] = 0.0f;

    // wave w stages A panel w and B panels 2w, 2w+1: 6 linear DMAs per K-step.
    const unsigned char* gaBase  = At + (size_t)(bm * 4 + w)      * (KT2 * 2048);
    const unsigned char* gbBase0 = Bt + (size_t)(bn * 8 + w * 2)  * (KT2 * 2048);
    const unsigned char* gbBase1 = gbBase0 + (size_t)(KT2 * 2048);

    auto stage = [&](int buf, int k) {
        unsigned char* As = sm + buf * 24576;
        unsigned char* Bs = As + 8192;
        const unsigned char* ga  = gaBase  + k * 2048;
        const unsigned char* gb0 = gbBase0 + k * 2048;
        const unsigned char* gb1 = gbBase1 + k * 2048;
        #pragma unroll
        for (int h = 0; h < 2; ++h) {
            async_copy16(ga  + h * 1024 + l * 16, As + w * 2048 + h * 1024);
            async_copy16(gb0 + h * 1024 + l * 16, Bs + (w * 2 + 0) * 2048 + h * 1024);
            async_copy16(gb1 + h * 1024 + l * 16, Bs + (w * 2 + 1) * 2048 + h * 1024);
        }
    };

    auto ldfrag = [&](const unsigned char* base, int p) -> i32x8 {
        i32x4 lo = *(const i32x4*)(base + p * 2048 + l * 16);
        i32x4 hi = *(const i32x4*)(base + p * 2048 + 1024 + l * 16);
        i32x8 r;
        r[0] = lo[0]; r[1] = lo[1]; r[2] = lo[2]; r[3] = lo[3];
        r[4] = hi[0]; r[5] = hi[1]; r[6] = hi[2]; r[7] = hi[3];
        return r;
    };

    stage(0, 0);              // 6 DMAs
    stage(1, 1);              // 6 DMAs  (12 in flight)

    int cb = 0, sb = 2;       // compute buf = k%3, stage buf = (k+2)%3
    for (int k = 0; k < 16; ++k) {
        // own stage(k) retired: outstanding = stage(k)+stage(k+1) = 12 -> wait
        // to 6 (stage(k) is the oldest 6). Never drain to 0 mid-loop.
        if (k < 15) asm volatile("s_waitcnt vmcnt(6)" ::: "memory");
        else        asm volatile("s_waitcnt vmcnt(0)" ::: "memory");
        __builtin_amdgcn_s_barrier();              // all waves' stage(k) landed
        __builtin_amdgcn_sched_barrier(0);         // no ds_read hoists above

        // WAR-safe: buf (k+2)%3 last read at iter k-1; barrier above orders it.
        if (k <= 13) stage(sb, k + 2);

        const unsigned char* As = sm + cb * 24576;
        const unsigned char* Bs = As + 8192;
        i32x8 bf0 = ldfrag(Bs, w * 2 + 0);
        i32x8 bf1 = ldfrag(Bs, w * 2 + 1);
        i32x8 af[4];
        #pragma unroll
        for (int mi = 0; mi < 4; ++mi)
            af[mi] = ldfrag(As, mi);

        __builtin_amdgcn_s_setprio(1);
        #pragma unroll
        for (int mi = 0; mi < 4; ++mi) {
            acc[mi][0] = __builtin_amdgcn_mfma_scale_f32_32x32x64_f8f6f4(
                af[mi], bf0, acc[mi][0],
                0, 0,                 // cbsz=fp8(e4m3), blgp=fp8(e4m3)
                0, 0x7F7F7F7F,        // A scales = 1.0 (E8M0 127)
                0, 0x7F7F7F7F);       // B scales = 1.0
            acc[mi][1] = __builtin_amdgcn_mfma_scale_f32_32x32x64_f8f6f4(
                af[mi], bf1, acc[mi][1],
                0, 0, 0, 0x7F7F7F7F, 0, 0x7F7F7F7F);
        }
        __builtin_amdgcn_s_setprio(0);

        cb = (cb == 2) ? 0 : cb + 1;
        sb = (sb == 2) ? 0 : sb + 1;
    }

    // Epilogue. 32x32 C/D layout: col(n)=lane&31, row(m)=(r&3)+8*(r>>2)+4*(l>>5).
    const int ncol = bn * 256 + w * 64 + l32;
    const float wsn0 = wsq2[ncol]      + wsq2[OUT_DIM + ncol]
                     + wsq2[2 * OUT_DIM + ncol]      + wsq2[3 * OUT_DIM + ncol];
    const float wsn1 = wsq2[ncol + 32] + wsq2[OUT_DIM + ncol + 32]
                     + wsq2[2 * OUT_DIM + ncol + 32] + wsq2[3 * OUT_DIM + ncol + 32];
    #pragma unroll
    for (int mi = 0; mi < 4; ++mi) {
        const int mbase = bm * 128 + mi * 32 + 4 * half;
        #pragma unroll
        for (int r2 = 0; r2 < 4; ++r2) {
            #pragma unroll
            for (int r1 = 0; r1 < 4; ++r1) {
                const int m  = mbase + r1 + 8 * r2;
                const float xs = xsq2[m] + xsq2[B_DIM + m];
                float* orow = out + (size_t)m * OUT_DIM + ncol;
                orow[0]  = xs + wsn0 - 2.0f * acc[mi][0][r2 * 4 + r1];
                orow[32] = xs + wsn1 - 2.0f * acc[mi][1][r2 * 4 + r1];
            }
        }
    }
}

// ---------------------------------------------------------------------------
extern "C" void kernel_launch(void* const* d_in, const int* in_sizes, int n_in,
                              void* d_out, int out_size, void* d_ws, size_t ws_size,
                              hipStream_t stream)
{
    const float* x   = (const float*)d_in[0];   // (8192, 1024) fp32
    const float* wgt = (const float*)d_in[1];   // (1024, 4096) fp32
    float* out = (float*)d_out;                 // (8192, 4096) fp32
    char*  ws  = (char*)d_ws;

    // workspace: At (8 MB) | Bt (4 MB) | xsq2 (64 KB) | wsq2 (64 KB)
    unsigned char* At = (unsigned char*)ws;
    unsigned char* Bt = (unsigned char*)(ws + (size_t)B_DIM * IN_DIM);
    float* xsq2 = (float*)(ws + (size_t)B_DIM * IN_DIM + (size_t)OUT_DIM * IN_DIM);
    float* wsq2 = xsq2 + 2 * B_DIM;

    quant_kernel<<<1024, 256, 0, stream>>>(x, wgt, At, Bt, xsq2, wsq2);
    rbf_gemm_kernel<<<dim3(64, 16), 256, 0, stream>>>(At, Bt, xsq2, wsq2, out);
}